// Round 2
// baseline (527.393 us; speedup 1.0000x reference)
//
#include <hip/hip_runtime.h>
#include <stdint.h>

#define D   512
#define BM  128
#define BN  128
#define BK  64

typedef __attribute__((ext_vector_type(8))) short short8;   // 8 bf16 = 4 VGPRs
typedef __attribute__((ext_vector_type(4))) float f32x4;    // MFMA accumulator

__device__ __forceinline__ void gld_lds16(const void* g, void* l) {
  __builtin_amdgcn_global_load_lds(
      (const __attribute__((address_space(1))) void*)g,
      (__attribute__((address_space(3))) void*)l, 16, 0, 0);
}

__device__ __forceinline__ unsigned short f2bf(float f) {
  unsigned u = __float_as_uint(f);
  u += 0x7fffu + ((u >> 16) & 1u);           // round-to-nearest-even
  return (unsigned short)(u >> 16);
}

// One wave per row: load 512 fp32, shuffle-reduce sum of squares, store 512 bf16.
// Block 0 thread 0 also zeroes the output accumulator (gemm is stream-ordered after us).
__global__ void norm_kernel(const float* __restrict__ img,
                            const float* __restrict__ prof,
                            unsigned short* __restrict__ outA,
                            unsigned short* __restrict__ outB,
                            float* __restrict__ out, int n) {
  if (blockIdx.x == 0 && threadIdx.x == 0) out[0] = 0.0f;
  int wave = threadIdx.x >> 6, lane = threadIdx.x & 63;
  int gw = blockIdx.x * 4 + wave;
  if (gw >= 2 * n) return;
  const float* src;
  unsigned short* dst;
  if (gw < n) { src = img  + (size_t)gw * D;       dst = outA + (size_t)gw * D; }
  else        { src = prof + (size_t)(gw - n) * D; dst = outB + (size_t)(gw - n) * D; }

  const float4* s4 = (const float4*)src + lane * 2;
  float4 a = s4[0], b = s4[1];
  float ss = a.x*a.x + a.y*a.y + a.z*a.z + a.w*a.w
           + b.x*b.x + b.y*b.y + b.z*b.z + b.w*b.w;
#pragma unroll
  for (int m = 1; m < 64; m <<= 1) ss += __shfl_xor(ss, m, 64);
  float inv = 1.0f / fmaxf(sqrtf(ss), 1e-12f);

  unsigned short h0 = f2bf(a.x*inv), h1 = f2bf(a.y*inv), h2 = f2bf(a.z*inv), h3 = f2bf(a.w*inv);
  unsigned short h4 = f2bf(b.x*inv), h5 = f2bf(b.y*inv), h6 = f2bf(b.z*inv), h7 = f2bf(b.w*inv);
  uint4 pk;
  pk.x = (unsigned)h0 | ((unsigned)h1 << 16);
  pk.y = (unsigned)h2 | ((unsigned)h3 << 16);
  pk.z = (unsigned)h4 | ((unsigned)h5 << 16);
  pk.w = (unsigned)h6 | ((unsigned)h7 << 16);
  *(uint4*)(dst + lane * 8) = pk;
}

// softplus(x) = log(1+e^x). For |x|>5: log1p(t)=t-t^2/2+O(t^3), t=e^-|x| < 6.7e-3
// -> abs err < t^3/3 < 1.1e-7 per element (and for this problem |x|>=7.28 always,
// since |sim|<=1 => x = +/-(e*sim-10) is outside (-7.28,7.28)). Precise path kept
// for safety; branch is wave-coherent and never taken here (s_cbranch_execz skip).
__device__ __forceinline__ float softplus_f(float x) {
  float ax = fabsf(x);
  float t = __expf(-ax);
  float corr;
  if (__builtin_expect(ax < 5.0f, 0)) corr = __logf(1.0f + t);
  else                                corr = t - 0.5f * t * t;
  return fmaxf(x, 0.0f) + corr;
}

// C = A(img) x B(prof)^T on bf16, fused SigLIP loss epilogue.
// LDS layout per tile: slot c (16B chunks) = row*8 + (kb ^ (row&7))  [xor swizzle]
//
// XCD-aware tile mapping: hardware dispatch round-robins blockIdx across the 8
// XCDs (xcd = blockIdx % 8, m09). We give each XCD a 16-block-row strip of C and
// sweep columns: its A-strip (16 panels x 128 KB = 2 MB) stays resident in its
// 4 MB L2, B streams one 128 KB panel at a time with 16x reuse. If the mapping
// assumption breaks, only locality suffers — correctness is unaffected.
__global__ __launch_bounds__(256) void siglip_gemm(
    const unsigned short* __restrict__ A, const unsigned short* __restrict__ B,
    const float* __restrict__ scale_p, const float* __restrict__ bias_p,
    const int* __restrict__ buckets_p, float* __restrict__ out, int n) {
  __shared__ __align__(16) unsigned short sA[BM * BK];
  __shared__ __align__(16) unsigned short sB[BN * BK];
  __shared__ float red[4];

  int tid = threadIdx.x;
  int lane = tid & 63, wave = tid >> 6;
  int quad = lane >> 4, l16 = lane & 15;

  int nb = n / BM;                       // blocks per dim (128)
  int bm, bn;
  int nstrips = nb >> 4;                 // 8 strips of 16 block-rows
  if ((nb & 15) == 0 && nstrips > 0) {
    int strip = blockIdx.x % nstrips;    // == XCD id under round-robin dispatch
    int idx   = blockIdx.x / nstrips;    // order within strip: column-major
    int col   = idx >> 4;
    int rowin = idx & 15;
    bm = strip * 16 + rowin;
    bn = col;
  } else {
    bm = blockIdx.x % nb;
    bn = blockIdx.x / nb;
  }

  int rowB = bm * BM, colB = bn * BN;
  const unsigned short* Ag = A + (size_t)rowB * D;
  const unsigned short* Bg = B + (size_t)colB * D;

  // scalar params (latency hidden under GEMM)
  float scale = __expf(scale_p[0]);
  float bias  = bias_p[0];
  int buckets = buckets_p[0];

  int wm = (wave >> 1) * 64, wn = (wave & 1) * 64;

  f32x4 acc[4][4];
#pragma unroll
  for (int i = 0; i < 4; i++)
#pragma unroll
    for (int j = 0; j < 4; j++) { acc[i][j].x = 0.f; acc[i][j].y = 0.f; acc[i][j].z = 0.f; acc[i][j].w = 0.f; }

  for (int k0 = 0; k0 < D; k0 += BK) {
    // stage A then B: 1024 chunks each, 4 per thread per matrix
#pragma unroll
    for (int p = 0; p < 4; p++) {
      int c = p * 256 + tid;
      int r = c >> 3, j = c & 7;
      int kb = j ^ (r & 7);
      gld_lds16(Ag + (size_t)r * D + k0 + kb * 8, &sA[c * 8]);
    }
#pragma unroll
    for (int p = 0; p < 4; p++) {
      int c = p * 256 + tid;
      int r = c >> 3, j = c & 7;
      int kb = j ^ (r & 7);
      gld_lds16(Bg + (size_t)r * D + k0 + kb * 8, &sB[c * 8]);
    }
    __syncthreads();   // compiler emits vmcnt(0) drain before barrier

#pragma unroll
    for (int ks = 0; ks < 2; ks++) {
      int kb = ks * 4 + quad;
      short8 af[4], bf[4];
#pragma unroll
      for (int t = 0; t < 4; t++) {
        int ra = wm + t * 16 + l16;
        af[t] = *(const short8*)&sA[(ra * 8 + (kb ^ (ra & 7))) * 8];
        int rb = wn + t * 16 + l16;
        bf[t] = *(const short8*)&sB[(rb * 8 + (kb ^ (rb & 7))) * 8];
      }
#pragma unroll
      for (int tm = 0; tm < 4; tm++)
#pragma unroll
        for (int tn = 0; tn < 4; tn++)
          acc[tm][tn] = __builtin_amdgcn_mfma_f32_16x16x32_bf16(af[tm], bf[tn], acc[tm][tn], 0, 0, 0);
    }
    __syncthreads();
  }

  // ---- fused loss epilogue ----
  // C/D layout (m89/m91): col = lane&15, row = quad*4 + reg
  float local = 0.0f;
  if (buckets == 1) {
#pragma unroll
    for (int tm = 0; tm < 4; tm++)
#pragma unroll
      for (int tn = 0; tn < 4; tn++)
#pragma unroll
        for (int e = 0; e < 4; e++) {
          int r = rowB + wm + tm * 16 + quad * 4 + e;
          int c = colB + wn + tn * 16 + l16;
          float v = acc[tm][tn][e] * scale + bias;
          // z = diag ? v : -v ; contribution = softplus(-z)
          float x = (r == c) ? -v : v;
          local += softplus_f(x);
        }
  } else {
    unsigned bs = (unsigned)n / (unsigned)buckets;
#pragma unroll
    for (int tm = 0; tm < 4; tm++)
#pragma unroll
      for (int tn = 0; tn < 4; tn++)
#pragma unroll
        for (int e = 0; e < 4; e++) {
          int r = rowB + wm + tm * 16 + quad * 4 + e;
          int c = colB + wn + tn * 16 + l16;
          if ((unsigned)r / bs != (unsigned)c / bs) continue;
          float v = acc[tm][tn][e] * scale + bias;
          float x = (r == c) ? -v : v;
          local += softplus_f(x);
        }
  }

#pragma unroll
  for (int m = 1; m < 64; m <<= 1) local += __shfl_xor(local, m, 64);
  if (lane == 0) red[wave] = local;
  __syncthreads();
  if (tid == 0) {
    float bsum = red[0] + red[1] + red[2] + red[3];
    atomicAdd(out, bsum * (1.0f / (float)n));   // /bs then mean over buckets == /n
  }
}

extern "C" void kernel_launch(void* const* d_in, const int* in_sizes, int n_in,
                              void* d_out, int out_size, void* d_ws, size_t ws_size,
                              hipStream_t stream) {
  const float* img  = (const float*)d_in[0];
  const float* prof = (const float*)d_in[1];
  const float* lsc  = (const float*)d_in[2];
  const float* bia  = (const float*)d_in[3];
  const int*   bkt  = (const int*)d_in[4];
  float* out = (float*)d_out;

  int n = in_sizes[0] / D;                       // 16384
  unsigned short* wsA = (unsigned short*)d_ws;   // n*512 bf16
  unsigned short* wsB = wsA + (size_t)n * D;     // n*512 bf16

  norm_kernel<<<(2 * n + 3) / 4, 256, 0, stream>>>(img, prof, wsA, wsB, out, n);
  int nb = n / BM;
  siglip_gemm<<<nb * nb, 256, 0, stream>>>(wsA, wsB, lsc, bia, bkt, out, n);
}

// Round 3
// 335.015 us; speedup vs baseline: 1.5742x; 1.5742x over previous
//
#include <hip/hip_runtime.h>
#include <stdint.h>

#define D   512      // embedding dim; also bytes per row in fp8
#define BM  128
#define BN  128
#define BKB 128      // K-elements (=bytes) staged per tile iteration

typedef __attribute__((ext_vector_type(4))) float f32x4;   // MFMA accumulator

__device__ __forceinline__ void gld_lds16(const void* g, void* l) {
  __builtin_amdgcn_global_load_lds(
      (const __attribute__((address_space(1))) void*)g,
      (__attribute__((address_space(3))) void*)l, 16, 0, 0);
}

// One wave per row: load 512 fp32, shuffle-reduce sumsq, write 512 fp8 (e4m3, x16).
// Pre-scale by 16 keeps values in e4m3 normal range (elems ~N(0,1/512) -> ~0.7 rms);
// undone by scale/256 in the GEMM epilogue (exact, power of 2).
// Block 0 thread 0 also zeroes the output accumulator (gemm is stream-ordered after).
__global__ void norm_kernel(const float* __restrict__ img,
                            const float* __restrict__ prof,
                            uint8_t* __restrict__ outA,
                            uint8_t* __restrict__ outB,
                            float* __restrict__ out, int n) {
  if (blockIdx.x == 0 && threadIdx.x == 0) out[0] = 0.0f;
  int wave = threadIdx.x >> 6, lane = threadIdx.x & 63;
  int gw = blockIdx.x * 4 + wave;
  if (gw >= 2 * n) return;
  const float* src;
  uint8_t* dst;
  if (gw < n) { src = img  + (size_t)gw * D; dst = outA + (size_t)gw * D; }
  else        { src = prof + (size_t)(gw - n) * D; dst = outB + (size_t)(gw - n) * D; }

  const float4* s4 = (const float4*)src + lane * 2;
  float4 a = s4[0], b = s4[1];
  float ss = a.x*a.x + a.y*a.y + a.z*a.z + a.w*a.w
           + b.x*b.x + b.y*b.y + b.z*b.z + b.w*b.w;
#pragma unroll
  for (int m = 1; m < 64; m <<= 1) ss += __shfl_xor(ss, m, 64);
  float inv = 16.0f / fmaxf(sqrtf(ss), 1e-12f);

  // v_cvt_pk_fp8_f32: within-pair byte order is irrelevant — A and B use the
  // identical packing, so any fixed K-permutation cancels in the dot product.
  uint32_t lo = __builtin_amdgcn_cvt_pk_fp8_f32(a.x*inv, a.y*inv, 0,  false);
  lo          = __builtin_amdgcn_cvt_pk_fp8_f32(a.z*inv, a.w*inv, lo, true);
  uint32_t hi = __builtin_amdgcn_cvt_pk_fp8_f32(b.x*inv, b.y*inv, 0,  false);
  hi          = __builtin_amdgcn_cvt_pk_fp8_f32(b.z*inv, b.w*inv, hi, true);
  uint2 pk; pk.x = lo; pk.y = hi;
  *(uint2*)(dst + lane * 8) = pk;
}

// softplus(x)=log(1+e^x). Here |x|>=7.28 always (|sim|<=1 => x outside (-7.28,7.28)),
// so the series corr = t - t^2/2, t = e^-|x|, is exact to ~1e-7. Precise branch kept
// for safety; wave-coherent, never taken (s_cbranch_execz skip).
__device__ __forceinline__ float softplus_f(float x) {
  float ax = fabsf(x);
  float t = __expf(-ax);
  float corr;
  if (__builtin_expect(ax < 5.0f, 0)) corr = __logf(1.0f + t);
  else                                corr = t - 0.5f * t * t;
  return fmaxf(x, 0.0f) + corr;
}

// C = A(img) x B(prof)^T in fp8 e4m3 (16x16x32 MFMA), fused SigLIP loss epilogue.
//
// LDS layout per tile row (128 B = exactly 32 banks): 8 chunks of 16 B, stored at
// slot s holding global k-chunk j = s ^ (r&7). Read of 8B k-piece kb (0..15):
// slot (kb>>1)^(r&7), byte offset (kb&1)*8 -> l16 lanes spread over 8 banks 2-way
// (free, m136). Staging keeps the wave-uniform-base + lane*16 contract of
// global_load_lds: LDS addr is linear in thread id; the swizzle permutes the
// GLOBAL chunk each slot receives.
//
// XCD strip mapping (r2: halved FETCH_SIZE): each XCD owns a 16-block-row strip,
// sweeps columns; A-strip ~1 MB resident in its L2, B streams with 16x reuse.
__global__ __launch_bounds__(256, 3) void siglip_gemm(
    const uint8_t* __restrict__ A, const uint8_t* __restrict__ B,
    const float* __restrict__ scale_p, const float* __restrict__ bias_p,
    const int* __restrict__ buckets_p, float* __restrict__ out, int n) {
  __shared__ __align__(16) uint8_t sA[BM * BKB];   // 16 KB
  __shared__ __align__(16) uint8_t sB[BN * BKB];   // 16 KB
  __shared__ float red[4];

  int tid = threadIdx.x;
  int lane = tid & 63, wave = tid >> 6;
  int quad = lane >> 4, l16 = lane & 15;

  int nb = n / BM;
  int bm, bn;
  int nstrips = nb >> 4;
  if ((nb & 15) == 0 && nstrips > 0) {
    int strip = blockIdx.x % nstrips;    // == XCD id under round-robin dispatch
    int idx   = blockIdx.x / nstrips;
    bm = strip * 16 + (idx & 15);
    bn = idx >> 4;
  } else {
    bm = blockIdx.x % nb;
    bn = blockIdx.x / nb;
  }

  int rowB = bm * BM, colB = bn * BN;
  const uint8_t* Ag = A + (size_t)rowB * D;
  const uint8_t* Bg = B + (size_t)colB * D;

  float scale = __expf(scale_p[0]) * (1.0f / 256.0f);   // undo x16 quant pre-scale
  float bias  = bias_p[0];
  int buckets = buckets_p[0];

  int wm = (wave >> 1) * 64, wn = (wave & 1) * 64;

  f32x4 acc[4][4];
#pragma unroll
  for (int i = 0; i < 4; i++)
#pragma unroll
    for (int j = 0; j < 4; j++) { acc[i][j].x = 0.f; acc[i][j].y = 0.f; acc[i][j].z = 0.f; acc[i][j].w = 0.f; }

  for (int k0 = 0; k0 < D; k0 += BKB) {   // 4 iterations
    // stage A and B: 1024 16B-chunks each, 4 per thread per matrix
#pragma unroll
    for (int p = 0; p < 4; p++) {
      int c = p * 256 + tid;
      int r = c >> 3, s = c & 7;
      int j = s ^ (r & 7);
      gld_lds16(Ag + (size_t)r * D + k0 + j * 16, &sA[c * 16]);
    }
#pragma unroll
    for (int p = 0; p < 4; p++) {
      int c = p * 256 + tid;
      int r = c >> 3, s = c & 7;
      int j = s ^ (r & 7);
      gld_lds16(Bg + (size_t)r * D + k0 + j * 16, &sB[c * 16]);
    }
    __syncthreads();

    for (int ks = 0; ks < 4; ks++) {
      int kb = ks * 4 + quad;              // 8B k-piece index, 0..15
      int off8 = (kb & 1) * 8;
      int jk = kb >> 1;
      long af[4], bf[4];
#pragma unroll
      for (int t = 0; t < 4; t++) {
        int ra = wm + t * 16 + l16;
        af[t] = *(const long*)&sA[ra * BKB + ((jk ^ (ra & 7)) * 16) + off8];
        int rb = wn + t * 16 + l16;
        bf[t] = *(const long*)&sB[rb * BKB + ((jk ^ (rb & 7)) * 16) + off8];
      }
#pragma unroll
      for (int tm = 0; tm < 4; tm++)
#pragma unroll
        for (int tn = 0; tn < 4; tn++)
          acc[tm][tn] = __builtin_amdgcn_mfma_f32_16x16x32_fp8_fp8(af[tm], bf[tn], acc[tm][tn], 0, 0, 0);
    }
    __syncthreads();
  }

  // ---- fused loss epilogue ----
  // C/D layout (m89/m121): col = lane&15, row = quad*4 + reg  (dtype-independent)
  float local = 0.0f;
  if (buckets == 1) {
#pragma unroll
    for (int tm = 0; tm < 4; tm++)
#pragma unroll
      for (int tn = 0; tn < 4; tn++)
#pragma unroll
        for (int e = 0; e < 4; e++) {
          int r = rowB + wm + tm * 16 + quad * 4 + e;
          int c = colB + wn + tn * 16 + l16;
          float v = acc[tm][tn][e] * scale + bias;
          float x = (r == c) ? -v : v;     // contribution = softplus(-z)
          local += softplus_f(x);
        }
  } else {
    unsigned bs = (unsigned)n / (unsigned)buckets;
#pragma unroll
    for (int tm = 0; tm < 4; tm++)
#pragma unroll
      for (int tn = 0; tn < 4; tn++)
#pragma unroll
        for (int e = 0; e < 4; e++) {
          int r = rowB + wm + tm * 16 + quad * 4 + e;
          int c = colB + wn + tn * 16 + l16;
          if ((unsigned)r / bs != (unsigned)c / bs) continue;
          float v = acc[tm][tn][e] * scale + bias;
          float x = (r == c) ? -v : v;
          local += softplus_f(x);
        }
  }

#pragma unroll
  for (int m = 1; m < 64; m <<= 1) local += __shfl_xor(local, m, 64);
  if (lane == 0) red[wave] = local;
  __syncthreads();
  if (tid == 0) {
    float bsum = red[0] + red[1] + red[2] + red[3];
    atomicAdd(out, bsum * (1.0f / (float)n));
  }
}

extern "C" void kernel_launch(void* const* d_in, const int* in_sizes, int n_in,
                              void* d_out, int out_size, void* d_ws, size_t ws_size,
                              hipStream_t stream) {
  const float* img  = (const float*)d_in[0];
  const float* prof = (const float*)d_in[1];
  const float* lsc  = (const float*)d_in[2];
  const float* bia  = (const float*)d_in[3];
  const int*   bkt  = (const int*)d_in[4];
  float* out = (float*)d_out;

  int n = in_sizes[0] / D;                 // 16384
  uint8_t* wsA = (uint8_t*)d_ws;           // n*512 fp8
  uint8_t* wsB = wsA + (size_t)n * D;      // n*512 fp8

  norm_kernel<<<(2 * n + 3) / 4, 256, 0, stream>>>(img, prof, wsA, wsB, out, n);
  int nb = n / BM;
  siglip_gemm<<<nb * nb, 256, 0, stream>>>(wsA, wsB, lsc, bia, bkt, out, n);
}

// Round 4
// 328.111 us; speedup vs baseline: 1.6074x; 1.0210x over previous
//
#include <hip/hip_runtime.h>
#include <stdint.h>

#define D   512      // embedding dim; also bytes per row in fp8
#define BM  128
#define BN  128
#define BKB 128      // K-bytes staged per tile iteration = one MX MFMA k-step

typedef __attribute__((ext_vector_type(4))) float f32x4;   // MFMA accumulator
typedef __attribute__((ext_vector_type(8))) int  i32x8;    // 32B MX A/B fragment

union frag32 { i32x8 v; uint4 q[2]; };

__device__ __forceinline__ void gld_lds16(const void* g, void* l) {
  __builtin_amdgcn_global_load_lds(
      (const __attribute__((address_space(1))) void*)g,
      (__attribute__((address_space(3))) void*)l, 16, 0, 0);
}

// One wave per row: load 512 fp32, shuffle-reduce sumsq, write 512 fp8 (e4m3, x16).
// Pre-scale by 16 keeps values in e4m3 normal range (elems ~N(0,1/512) -> ~0.7 rms);
// undone by scale/256 in the GEMM epilogue (exact, power of 2).
// Block 0 thread 0 also zeroes the output accumulator (gemm is stream-ordered after).
__global__ void norm_kernel(const float* __restrict__ img,
                            const float* __restrict__ prof,
                            uint8_t* __restrict__ outA,
                            uint8_t* __restrict__ outB,
                            float* __restrict__ out, int n) {
  if (blockIdx.x == 0 && threadIdx.x == 0) out[0] = 0.0f;
  int wave = threadIdx.x >> 6, lane = threadIdx.x & 63;
  int gw = blockIdx.x * 4 + wave;
  if (gw >= 2 * n) return;
  const float* src;
  uint8_t* dst;
  if (gw < n) { src = img  + (size_t)gw * D; dst = outA + (size_t)gw * D; }
  else        { src = prof + (size_t)(gw - n) * D; dst = outB + (size_t)(gw - n) * D; }

  const float4* s4 = (const float4*)src + lane * 2;
  float4 a = s4[0], b = s4[1];
  float ss = a.x*a.x + a.y*a.y + a.z*a.z + a.w*a.w
           + b.x*b.x + b.y*b.y + b.z*b.z + b.w*b.w;
#pragma unroll
  for (int m = 1; m < 64; m <<= 1) ss += __shfl_xor(ss, m, 64);
  float inv = 16.0f / fmaxf(sqrtf(ss), 1e-12f);

  // Within-pair byte order of cvt_pk is irrelevant: A and B use identical packing,
  // so any fixed K-permutation cancels in the dot product.
  uint32_t lo = __builtin_amdgcn_cvt_pk_fp8_f32(a.x*inv, a.y*inv, 0,  false);
  lo          = __builtin_amdgcn_cvt_pk_fp8_f32(a.z*inv, a.w*inv, lo, true);
  uint32_t hi = __builtin_amdgcn_cvt_pk_fp8_f32(b.x*inv, b.y*inv, 0,  false);
  hi          = __builtin_amdgcn_cvt_pk_fp8_f32(b.z*inv, b.w*inv, hi, true);
  uint2 pk; pk.x = lo; pk.y = hi;
  *(uint2*)(dst + lane * 8) = pk;
}

// softplus(x)=log(1+e^x). Here |x|>=7.28 always (|sim|<=1 => x outside (-7.28,7.28)),
// so the series corr = t - t^2/2, t = e^-|x|, is exact to ~1e-7. Precise branch kept
// for safety; wave-coherent, never taken (s_cbranch_execz skip).
__device__ __forceinline__ float softplus_f(float x) {
  float ax = fabsf(x);
  float t = __expf(-ax);
  float corr;
  if (__builtin_expect(ax < 5.0f, 0)) corr = __logf(1.0f + t);
  else                                corr = t - 0.5f * t * t;
  return fmaxf(x, 0.0f) + corr;
}

// C = A(img) x B(prof)^T in fp8 e4m3 via MX-scaled MFMA 16x16x128 with unit scales
// (e8m0=127 -> x2^0: numerically identical to plain fp8, 2.3x the MFMA rate, m21/m148).
// A-frag layout: m = lane&15, k = quad*32 + byte (32 contiguous bytes/lane).
//
// LDS layout per tile row (128 B = 8 chunks of 16 B): chunk j stored at slot
// j ^ (r&7). Frag read = two ds_read_b128 at slots (2q)^(r&7), (2q+1)^(r&7):
// each quad's 16 lanes cover all 8 slots (all 32 banks), whole wave = 8 distinct
// addresses/bank = the structural minimum for wave64 b128 (64 lanes x 16 B).
// Staging keeps the wave-uniform-base + lane*16 contract of global_load_lds.
//
// XCD strip mapping (r2: halved FETCH_SIZE): each XCD owns a 16-block-row strip,
// sweeps columns; A-strip stays resident in its L2, B streams with 16x reuse.
__global__ __launch_bounds__(256, 3) void siglip_gemm(
    const uint8_t* __restrict__ A, const uint8_t* __restrict__ B,
    const float* __restrict__ scale_p, const float* __restrict__ bias_p,
    const int* __restrict__ buckets_p, float* __restrict__ out, int n) {
  __shared__ __align__(16) uint8_t sA[BM * BKB];   // 16 KB
  __shared__ __align__(16) uint8_t sB[BN * BKB];   // 16 KB
  __shared__ float red[4];

  int tid = threadIdx.x;
  int lane = tid & 63, wave = tid >> 6;
  int quad = lane >> 4, l16 = lane & 15;

  int nb = n / BM;
  int bm, bn;
  int nstrips = nb >> 4;
  if ((nb & 15) == 0 && nstrips > 0) {
    int strip = blockIdx.x % nstrips;    // == XCD id under round-robin dispatch
    int idx   = blockIdx.x / nstrips;
    bm = strip * 16 + (idx & 15);
    bn = idx >> 4;
  } else {
    bm = blockIdx.x % nb;
    bn = blockIdx.x / nb;
  }

  int rowB = bm * BM, colB = bn * BN;
  const uint8_t* Ag = A + (size_t)rowB * D;
  const uint8_t* Bg = B + (size_t)colB * D;

  float scale = __expf(scale_p[0]) * (1.0f / 256.0f);   // undo x16 quant pre-scale
  float bias  = bias_p[0];
  int buckets = buckets_p[0];

  int wm = (wave >> 1) * 64, wn = (wave & 1) * 64;

  f32x4 acc[4][4];
#pragma unroll
  for (int i = 0; i < 4; i++)
#pragma unroll
    for (int j = 0; j < 4; j++) { acc[i][j].x = 0.f; acc[i][j].y = 0.f; acc[i][j].z = 0.f; acc[i][j].w = 0.f; }

  int c0 = quad * 2, c1 = quad * 2 + 1;   // 16B chunk indices this quad consumes

  for (int k0 = 0; k0 < D; k0 += BKB) {   // 4 iterations
    // stage A and B: 1024 16B-chunks each, 4 per thread per matrix
#pragma unroll
    for (int p = 0; p < 4; p++) {
      int c = p * 256 + tid;
      int r = c >> 3, s = c & 7;
      int j = s ^ (r & 7);
      gld_lds16(Ag + (size_t)r * D + k0 + j * 16, &sA[c * 16]);
    }
#pragma unroll
    for (int p = 0; p < 4; p++) {
      int c = p * 256 + tid;
      int r = c >> 3, s = c & 7;
      int j = s ^ (r & 7);
      gld_lds16(Bg + (size_t)r * D + k0 + j * 16, &sB[c * 16]);
    }
    __syncthreads();

    frag32 af[4], bf[4];
#pragma unroll
    for (int t = 0; t < 4; t++) {
      int ra = wm + t * 16 + l16, ea = ra & 7;
      af[t].q[0] = *(const uint4*)&sA[ra * BKB + ((c0 ^ ea) << 4)];
      af[t].q[1] = *(const uint4*)&sA[ra * BKB + ((c1 ^ ea) << 4)];
      int rb = wn + t * 16 + l16, eb = rb & 7;
      bf[t].q[0] = *(const uint4*)&sB[rb * BKB + ((c0 ^ eb) << 4)];
      bf[t].q[1] = *(const uint4*)&sB[rb * BKB + ((c1 ^ eb) << 4)];
    }
#pragma unroll
    for (int tm = 0; tm < 4; tm++)
#pragma unroll
      for (int tn = 0; tn < 4; tn++)
        acc[tm][tn] = __builtin_amdgcn_mfma_scale_f32_16x16x128_f8f6f4(
            af[tm].v, bf[tn].v, acc[tm][tn],
            0, 0,            // cbsz=0 (A=fp8 e4m3), blgp=0 (B=fp8 e4m3)
            0, 127,          // scale_src0: opsel 0, e8m0 127 -> 1.0
            0, 127);         // scale_src1: opsel 0, e8m0 127 -> 1.0
    __syncthreads();
  }

  // ---- fused loss epilogue ----
  // C/D layout: col = lane&15, row = quad*4 + reg (shape-determined, m121/m127)
  float local = 0.0f;
  if (buckets == 1) {
#pragma unroll
    for (int tm = 0; tm < 4; tm++)
#pragma unroll
      for (int tn = 0; tn < 4; tn++)
#pragma unroll
        for (int e = 0; e < 4; e++) {
          int r = rowB + wm + tm * 16 + quad * 4 + e;
          int c = colB + wn + tn * 16 + l16;
          float v = acc[tm][tn][e] * scale + bias;
          float x = (r == c) ? -v : v;     // contribution = softplus(-z)
          local += softplus_f(x);
        }
  } else {
    unsigned bs = (unsigned)n / (unsigned)buckets;
#pragma unroll
    for (int tm = 0; tm < 4; tm++)
#pragma unroll
      for (int tn = 0; tn < 4; tn++)
#pragma unroll
        for (int e = 0; e < 4; e++) {
          int r = rowB + wm + tm * 16 + quad * 4 + e;
          int c = colB + wn + tn * 16 + l16;
          if ((unsigned)r / bs != (unsigned)c / bs) continue;
          float v = acc[tm][tn][e] * scale + bias;
          float x = (r == c) ? -v : v;
          local += softplus_f(x);
        }
  }

#pragma unroll
  for (int m = 1; m < 64; m <<= 1) local += __shfl_xor(local, m, 64);
  if (lane == 0) red[wave] = local;
  __syncthreads();
  if (tid == 0) {
    float bsum = red[0] + red[1] + red[2] + red[3];
    atomicAdd(out, bsum * (1.0f / (float)n));
  }
}

extern "C" void kernel_launch(void* const* d_in, const int* in_sizes, int n_in,
                              void* d_out, int out_size, void* d_ws, size_t ws_size,
                              hipStream_t stream) {
  const float* img  = (const float*)d_in[0];
  const float* prof = (const float*)d_in[1];
  const float* lsc  = (const float*)d_in[2];
  const float* bia  = (const float*)d_in[3];
  const int*   bkt  = (const int*)d_in[4];
  float* out = (float*)d_out;

  int n = in_sizes[0] / D;                 // 16384
  uint8_t* wsA = (uint8_t*)d_ws;           // n*512 fp8
  uint8_t* wsB = wsA + (size_t)n * D;      // n*512 fp8

  norm_kernel<<<(2 * n + 3) / 4, 256, 0, stream>>>(img, prof, wsA, wsB, out, n);
  int nb = n / BM;
  siglip_gemm<<<nb * nb, 256, 0, stream>>>(wsA, wsB, lsc, bia, bkt, out, n);
}